// Round 14
// baseline (225.527 us; speedup 1.0000x reference)
//
#include <hip/hip_runtime.h>
#include <math.h>

#define L_SEQ 8192
#define NFFT  16384     // conv length
#define N2    8192      // packed complex FFT length
#define N4    4096      // half (radix-2 block) length
#define CCH   768
#define BB    4
#define EDIM  33
#define ODIM  64
#define BLK2  1024      // FFT kernels: 1024 threads -> 16 waves/WG, 2 WG/CU = 32 waves

// Kf pre-scale: 0.25 (unpack halves) * 1/16384 (fft norm) = 2^-16 (exact)
#define ALPHA 1.52587890625e-05f

// ---------- constexpr index helpers (GF(2)-linear) ----------
constexpr int rev4_12c(int v) {
  int r = 0;
  for (int i = 0; i < 6; ++i) { r = (r << 2) | (v & 3); v >>= 2; }
  return r;
}
constexpr int pos8c(int f) { return ((f & 1) << 12) | rev4_12c(f >> 1); }
constexpr int swzc(int i) { return i ^ ((i >> 4) & 15) ^ ((i >> 8) & 15); }

// ---------- complex helpers ----------
__device__ __forceinline__ float2 cadd(float2 a, float2 b) { return make_float2(a.x + b.x, a.y + b.y); }
__device__ __forceinline__ float2 csub(float2 a, float2 b) { return make_float2(a.x - b.x, a.y - b.y); }
__device__ __forceinline__ float2 cmul(float2 a, float2 b) {
  return make_float2(fmaf(a.x, b.x, -a.y * b.y), fmaf(a.x, b.y, a.y * b.x));
}
// a * conj(w)
__device__ __forceinline__ float2 cmulc(float2 a, float2 w) {
  return make_float2(fmaf(a.x, w.x, a.y * w.y), fmaf(a.y, w.x, -a.x * w.y));
}
__device__ __forceinline__ float2 cconj(float2 a) { return make_float2(a.x, -a.y); }

// ---------- radix-4 butterflies ----------
__device__ __forceinline__ void dif4(float2& x0, float2& x1, float2& x2, float2& x3,
                                     float2 w1, float2 w2, float2 w3) {
  float2 a = cadd(x0, x2), b = csub(x0, x2);
  float2 c = cadd(x1, x3), d = csub(x1, x3);
  x0 = cadd(a, c);
  x1 = cmul(make_float2(b.x + d.y, b.y - d.x), w1);
  x2 = cmul(csub(a, c), w2);
  x3 = cmul(make_float2(b.x - d.y, b.y + d.x), w3);
}
__device__ __forceinline__ void dif4_nw(float2& x0, float2& x1, float2& x2, float2& x3) {
  float2 a = cadd(x0, x2), b = csub(x0, x2);
  float2 c = cadd(x1, x3), d = csub(x1, x3);
  x0 = cadd(a, c);
  x1 = make_float2(b.x + d.y, b.y - d.x);
  x2 = csub(a, c);
  x3 = make_float2(b.x - d.y, b.y + d.x);
}
__device__ __forceinline__ void dit4(float2& x0, float2& x1, float2& x2, float2& x3,
                                     float2 w1, float2 w2, float2 w3) {
  float2 t0 = x0, t1 = cmulc(x1, w1), t2 = cmulc(x2, w2), t3 = cmulc(x3, w3);
  float2 a = cadd(t0, t2), b = csub(t0, t2);
  float2 c = cadd(t1, t3), d = csub(t1, t3);
  x0 = cadd(a, c);
  x1 = make_float2(b.x - d.y, b.y + d.x);
  x2 = csub(a, c);
  x3 = make_float2(b.x + d.y, b.y - d.x);
}
__device__ __forceinline__ void dit4_nw(float2& x0, float2& x1, float2& x2, float2& x3) {
  float2 a = cadd(x0, x2), b = csub(x0, x2);
  float2 c = cadd(x1, x3), d = csub(x1, x3);
  x0 = cadd(a, c);
  x1 = make_float2(b.x - d.y, b.y + d.x);
  x2 = csub(a, c);
  x3 = make_float2(b.x + d.y, b.y - d.x);
}

// triple-table read: entry = {w1, w2, w3, pad} as 2x float4
__device__ __forceinline__ void ld3(const float4* __restrict__ tab, int idx,
                                    float2& w1, float2& w2, float2& w3) {
  float4 a = tab[2 * idx];
  float4 b = tab[2 * idx + 1];
  w1 = make_float2(a.x, a.y);
  w2 = make_float2(a.z, a.w);
  w3 = make_float2(b.x, b.y);
}

// ---------- twiddle + triple tables (round-10 proven) ----------
// T4[i]  : e = 4i   (i < 1024)   [also T4[256u] -> e = 1024u]
// T16[i] : e = 16i  (i < 256)
// T64[i] : e = 64i  (i < 64)
// T256[i]: e = 256i (i < 16)
__global__ void twiddle_kernel(float2* __restrict__ tw, float4* __restrict__ T4,
                               float4* __restrict__ T16, float4* __restrict__ T64,
                               float4* __restrict__ T256) {
  const int r = blockIdx.x * blockDim.x + threadIdx.x;
  const float C = (float)(6.283185307179586476925286766559 / 16384.0);
  if (r < NFFT) {
    float s, c;
    sincosf(C * (float)r, &s, &c);
    tw[r] = make_float2(c, -s);
  }
  const int j = r - NFFT;
  float4* tab = nullptr;
  int idx = 0, e = 0;
  if (j >= 0 && j < 1024)      { tab = T4;   idx = j;        e = 4 * (j & 255) + 1024 * (j >> 8); }
  else if (j >= 1024 && j < 1280) { tab = T16;  idx = j - 1024; e = 16 * idx; }
  else if (j >= 1280 && j < 1344) { tab = T64;  idx = j - 1280; e = 64 * (idx & 15) + 1024 * (idx >> 4); }
  else if (j >= 1344 && j < 1360) { tab = T256; idx = j - 1344; e = 256 * idx; }
  if (tab) {
    float s1, c1, s2, c2, s3, c3;
    sincosf(C * (float)e, &s1, &c1);
    sincosf(C * (float)(2 * e), &s2, &c2);
    sincosf(C * (float)(3 * e), &s3, &c3);
    tab[2 * idx]     = make_float4(c1, -s1, c2, -s2);
    tab[2 * idx + 1] = make_float4(c3, -s3, 0.f, 0.f);
  }
}

// ---------- MLP (round-13 proven): 512 blocks x 128 threads ----------
#define ML 16
__global__ __launch_bounds__(128) void mlp_kernel(
    const float* __restrict__ z, const float* __restrict__ freq,
    const float* __restrict__ w0, const float* __restrict__ b0,
    const float* __restrict__ w1, const float* __restrict__ b1,
    const float* __restrict__ w2, const float* __restrict__ b2,
    float* __restrict__ h)            // [64][L]
{
  __shared__ float zs[ML][EDIM];
  __shared__ float hsA[ML][ODIM + 1];
  __shared__ float hsB[ML][ODIM + 1];
  const int tid = threadIdx.x;
  const int l0 = blockIdx.x * ML;
  const int lrow = tid & 15;
  const int oc = (tid >> 4) * 8;

  for (int idx = tid; idx < ML * EDIM; idx += 128) {
    int r = idx / EDIM, cc = idx - r * EDIM;
    zs[r][cc] = z[(l0 + r) * EDIM + cc];
  }
  __syncthreads();

  float acc[8], fr[8];
#pragma unroll
  for (int k = 0; k < 8; ++k) { fr[k] = freq[oc + k]; acc[k] = b0[oc + k]; }
#pragma unroll 4
  for (int e = 0; e < EDIM; ++e) {
    const float zv = zs[lrow][e];
#pragma unroll
    for (int j = 0; j < 2; ++j) {
      float4 w4 = *(const float4*)&w0[e * ODIM + oc + 4 * j];
      acc[4*j+0] = fmaf(zv, w4.x, acc[4*j+0]);
      acc[4*j+1] = fmaf(zv, w4.y, acc[4*j+1]);
      acc[4*j+2] = fmaf(zv, w4.z, acc[4*j+2]);
      acc[4*j+3] = fmaf(zv, w4.w, acc[4*j+3]);
    }
  }
#pragma unroll
  for (int k = 0; k < 8; ++k) hsA[lrow][oc + k] = sinf(fr[k] * acc[k]);
  __syncthreads();

#pragma unroll
  for (int k = 0; k < 8; ++k) acc[k] = b1[oc + k];
#pragma unroll 4
  for (int i = 0; i < ODIM; ++i) {
    const float hv = hsA[lrow][i];
#pragma unroll
    for (int j = 0; j < 2; ++j) {
      float4 w4 = *(const float4*)&w1[i * ODIM + oc + 4 * j];
      acc[4*j+0] = fmaf(hv, w4.x, acc[4*j+0]);
      acc[4*j+1] = fmaf(hv, w4.y, acc[4*j+1]);
      acc[4*j+2] = fmaf(hv, w4.z, acc[4*j+2]);
      acc[4*j+3] = fmaf(hv, w4.w, acc[4*j+3]);
    }
  }
#pragma unroll
  for (int k = 0; k < 8; ++k) hsB[lrow][oc + k] = sinf(fr[k] * acc[k]);
  __syncthreads();

#pragma unroll
  for (int k = 0; k < 8; ++k) acc[k] = b2[oc + k];
#pragma unroll 4
  for (int i = 0; i < ODIM; ++i) {
    const float hv = hsB[lrow][i];
#pragma unroll
    for (int j = 0; j < 2; ++j) {
      float4 w4 = *(const float4*)&w2[i * ODIM + oc + 4 * j];
      acc[4*j+0] = fmaf(hv, w4.x, acc[4*j+0]);
      acc[4*j+1] = fmaf(hv, w4.y, acc[4*j+1]);
      acc[4*j+2] = fmaf(hv, w4.z, acc[4*j+2]);
      acc[4*j+3] = fmaf(hv, w4.w, acc[4*j+3]);
    }
  }
#pragma unroll
  for (int k = 0; k < 8; ++k)
    h[(size_t)(oc + k) * L_SEQ + l0 + lrow] = sinf(fr[k] * acc[k]);
}

// ---------- kout: 64x64 tile, 4x4 register micro-tile (round-5 proven) ----------
__global__ __launch_bounds__(256) void kout_kernel(
    const float* __restrict__ h, const float* __restrict__ wout,
    const float* __restrict__ t, const float* __restrict__ deltas,
    float* __restrict__ k)            // [768][L]
{
  __shared__ float hT[ODIM][64];
  __shared__ float wT[ODIM][64];
  const int lb = blockIdx.x % (L_SEQ / 64);
  const int cb = blockIdx.x / (L_SEQ / 64);
  const int l0 = lb * 64, c0 = cb * 64;
  const int tid = threadIdx.x;
  for (int i = tid; i < ODIM * 16; i += 256) {
    int o = i >> 4, lq = (i & 15) * 4;
    *(float4*)&hT[o][lq] = *(const float4*)&h[(size_t)o * L_SEQ + l0 + lq];
  }
  for (int i = tid; i < ODIM * 16; i += 256) {
    int o = i >> 4, cq = (i & 15) * 4;
    *(float4*)&wT[o][cq] = *(const float4*)&wout[(size_t)o * CCH + c0 + cq];
  }
  __syncthreads();
  const int li = tid & 15, ci = tid >> 4;
  float acc[4][4];
#pragma unroll
  for (int a = 0; a < 4; ++a)
#pragma unroll
    for (int b = 0; b < 4; ++b) acc[a][b] = 0.f;
#pragma unroll 8
  for (int o = 0; o < ODIM; ++o) {
    float4 h4 = *(const float4*)&hT[o][li * 4];
    float4 w4 = *(const float4*)&wT[o][ci * 4];
    const float ha[4] = {h4.x, h4.y, h4.z, h4.w};
    const float wa[4] = {w4.x, w4.y, w4.z, w4.w};
#pragma unroll
    for (int a = 0; a < 4; ++a)
#pragma unroll
      for (int b = 0; b < 4; ++b) acc[a][b] = fmaf(ha[a], wa[b], acc[a][b]);
  }
  float4 t4 = *(const float4*)&t[l0 + li * 4];
  const float ta[4] = {t4.x, t4.y, t4.z, t4.w};
#pragma unroll
  for (int b = 0; b < 4; ++b) {
    const int c = c0 + ci * 4 + b;
    const float dl = fabsf(deltas[c]);
    float4 r;
    r.x = acc[0][b] * expf(-ta[0] * dl);
    r.y = acc[1][b] * expf(-ta[1] * dl);
    r.z = acc[2][b] * expf(-ta[2] * dl);
    r.w = acc[3][b] * expf(-ta[3] * dl);
    *(float4*)&k[(size_t)c * L_SEQ + l0 + li * 4] = r;
  }
}

// ---------- plain radix-4 stages, 1024 threads: one butterfly per half ----------
// Stage sequence (fwd m=1024,256,64,16,4,1; inv reverse) is IDENTICAL to the
// proven fused kernel, so layout/pos8c/swizzle/twiddle tables carry over.

template<int MLOG, int ISCALE>
__device__ __forceinline__ void stg_fwd(float2* __restrict__ Z,
                                        const float4* __restrict__ tab, int tid) {
  constexpr int M = 1 << MLOG;
  const int u = tid & (M - 1);
  const int sb = swzc(((tid >> MLOG) << (MLOG + 2)) | u);
  float2 w1, w2, w3;
  ld3(tab, u * ISCALE, w1, w2, w3);
#pragma unroll
  for (int h = 0; h < 2; ++h) {
    const int b = sb ^ (h << 12);
    float2 x0 = Z[b];
    float2 x1 = Z[b ^ swzc(M)];
    float2 x2v = Z[b ^ swzc(2 * M)];
    float2 x3 = Z[b ^ swzc(3 * M)];
    dif4(x0, x1, x2v, x3, w1, w2, w3);
    Z[b] = x0;
    Z[b ^ swzc(M)] = x1;
    Z[b ^ swzc(2 * M)] = x2v;
    Z[b ^ swzc(3 * M)] = x3;
  }
}

__device__ __forceinline__ void stg_fwd_m1(float2* __restrict__ Z, int tid) {
  const int sb = swzc(tid << 2);
#pragma unroll
  for (int h = 0; h < 2; ++h) {
    const int b = sb ^ (h << 12);
    float2 x0 = Z[b], x1 = Z[b ^ 1], x2v = Z[b ^ 2], x3 = Z[b ^ 3];
    dif4_nw(x0, x1, x2v, x3);
    Z[b] = x0; Z[b ^ 1] = x1; Z[b ^ 2] = x2v; Z[b ^ 3] = x3;
  }
}

template<int MLOG, int ISCALE>
__device__ __forceinline__ void stg_inv(float2* __restrict__ Z,
                                        const float4* __restrict__ tab, int tid) {
  constexpr int M = 1 << MLOG;
  const int u = tid & (M - 1);
  const int sb = swzc(((tid >> MLOG) << (MLOG + 2)) | u);
  float2 w1, w2, w3;
  ld3(tab, u * ISCALE, w1, w2, w3);
#pragma unroll
  for (int h = 0; h < 2; ++h) {
    const int b = sb ^ (h << 12);
    float2 x0 = Z[b];
    float2 x1 = Z[b ^ swzc(M)];
    float2 x2v = Z[b ^ swzc(2 * M)];
    float2 x3 = Z[b ^ swzc(3 * M)];
    dit4(x0, x1, x2v, x3, w1, w2, w3);
    Z[b] = x0;
    Z[b ^ swzc(M)] = x1;
    Z[b ^ swzc(2 * M)] = x2v;
    Z[b ^ swzc(3 * M)] = x3;
  }
}

__device__ __forceinline__ void stg_inv_m1(float2* __restrict__ Z, int tid) {
  const int sb = swzc(tid << 2);
#pragma unroll
  for (int h = 0; h < 2; ++h) {
    const int b = sb ^ (h << 12);
    float2 x0 = Z[b], x1 = Z[b ^ 1], x2v = Z[b ^ 2], x3 = Z[b ^ 3];
    dit4_nw(x0, x1, x2v, x3);
    Z[b] = x0; Z[b ^ 1] = x1; Z[b ^ 2] = x2v; Z[b ^ 3] = x3;
  }
}

// stage 1 (m=1024) fused with global load + entry radix-2 (shared loads)
__device__ __forceinline__ void fwd_stage1_load(float2* __restrict__ Z,
                                                const float2* __restrict__ src,
                                                const float2* __restrict__ tw,
                                                const float4* __restrict__ T4, int tid) {
  float2 g[4], o[4];
#pragma unroll
  for (int t = 0; t < 4; ++t) g[t] = src[tid + (t << 10)];
#pragma unroll
  for (int t = 0; t < 4; ++t) o[t] = cmul(g[t], tw[(tid + (t << 10)) << 1]);
  float2 w1, w2, w3;
  ld3(T4, tid, w1, w2, w3);
  dif4(g[0], g[1], g[2], g[3], w1, w2, w3);
  dif4(o[0], o[1], o[2], o[3], w1, w2, w3);
  const int sb = swzc(tid);
  Z[sb]              = g[0];
  Z[sb ^ swzc(1024)] = g[1];
  Z[sb ^ swzc(2048)] = g[2];
  Z[sb ^ swzc(3072)] = g[3];
  const int sc = sb ^ 4096;
  Z[sc]              = o[0];
  Z[sc ^ swzc(1024)] = o[1];
  Z[sc ^ swzc(2048)] = o[2];
  Z[sc ^ swzc(3072)] = o[3];
}

__device__ __forceinline__ void fft_fwd(float2* __restrict__ Z, const float2* __restrict__ src,
                                        const float2* __restrict__ tw,
                                        const float4* __restrict__ T4, const float4* __restrict__ T16,
                                        const float4* __restrict__ T64, const float4* __restrict__ T256,
                                        int tid) {
  fwd_stage1_load(Z, src, tw, T4, tid);
  __syncthreads();
  stg_fwd<8, 1>(Z, T16, tid);    // m=256, e=16u
  __syncthreads();
  stg_fwd<6, 1>(Z, T64, tid);    // m=64,  e=64u
  __syncthreads();
  stg_fwd<4, 1>(Z, T256, tid);   // m=16,  e=256u
  __syncthreads();
  stg_fwd<2, 256>(Z, T4, tid);   // m=4,   e=1024u (T4[256u])
  __syncthreads();
  stg_fwd_m1(Z, tid);            // m=1, twiddle-free
  __syncthreads();
}

// ---------- kfft: one channel per WG; store pre-scaled K half-spectrum ----------
__global__ __launch_bounds__(BLK2, 8) void kfft_kernel(
    const float* __restrict__ kf, const float2* __restrict__ tw,
    const float4* __restrict__ T4, const float4* __restrict__ T16,
    const float4* __restrict__ T64, const float4* __restrict__ T256,
    float2* __restrict__ Kf)
{
  extern __shared__ float2 Z[];
  const int c = blockIdx.x, tid = threadIdx.x;
  const float2* k2 = (const float2*)(kf + (size_t)c * L_SEQ);
  fft_fwd(Z, k2, tw, T4, T16, T64, T256, tid);

  float2* Kc = Kf + (size_t)c * N2;
  const int P0 = swzc(pos8c(tid));
  const int Q0 = swzc(pos8c(1024 - tid));
  const float beta = 0.5f * ALPHA;
#pragma unroll
  for (int s2 = 0; s2 < 4; ++s2) {
    if (s2 == 0 && tid == 0) {
      float2 z0 = Z[0];
      Kc[0] = make_float2(ALPHA * (z0.x + z0.y), ALPHA * (z0.x - z0.y));
      float2 z4 = Z[2];                       // pos8(4096) == 2
      Kc[N4] = make_float2(ALPHA * z4.x, -ALPHA * z4.y);
    } else {
      const int f = tid + (s2 << 10);
      const int p = P0 ^ swzc(pos8c(s2 << 10));
      const int pq = (tid == 0) ? swzc(pos8c((8 - s2) << 10))
                                : (Q0 ^ swzc(pos8c((7 - s2) << 10)));
      float2 zf = Z[p], zg = Z[pq];
      float2 E = make_float2(beta * (zf.x + zg.x), beta * (zf.y - zg.y));
      float2 O = make_float2(beta * (zf.y + zg.y), beta * (zg.x - zf.x));
      float2 wO = cmul(tw[f], O);
      Kc[f]      = cadd(E, wO);
      Kc[N2 - f] = cconj(csub(E, wO));
    }
  }
}

// ---------- conv: one (b,c) row per WG; 32 waves/CU ----------
__global__ __launch_bounds__(BLK2, 8) void conv_kernel(
    const float* __restrict__ x, const float2* __restrict__ Kf,
    const float* __restrict__ bias, const float2* __restrict__ tw,
    const float4* __restrict__ T4, const float4* __restrict__ T16,
    const float4* __restrict__ T64, const float4* __restrict__ T256,
    float* __restrict__ out)
{
  extern __shared__ float2 Z[];
  const int tid = threadIdx.x;
  const int c = blockIdx.x % CCH;
  const int b = blockIdx.x / CCH;
  const float2* x2 = (const float2*)(x + (size_t)(b * CCH + c) * L_SEQ);
  const float2* Kc = Kf + (size_t)c * N2;

  fft_fwd(Z, x2, tw, T4, T16, T64, T256, tid);

  // unpack X, multiply by pre-scaled K, repack (pairing within same half)
  const int P0 = swzc(pos8c(tid));
  const int Q0 = swzc(pos8c(1024 - tid));
#pragma unroll
  for (int s2 = 0; s2 < 4; ++s2) {
    if (s2 == 0 && tid == 0) {
      float2 z0 = Z[0];
      float2 k0 = Kc[0];
      float2 k4 = Kc[N4];
      float Y0 = (z0.x + z0.y) * k0.x;
      float Y8 = (z0.x - z0.y) * k0.y;
      Z[0] = make_float2(2.f * (Y0 + Y8), 2.f * (Y0 - Y8));
      float2 z4 = Z[2];
      float2 Y4 = cmul(make_float2(z4.x, -z4.y), k4);
      Z[2] = make_float2(4.f * Y4.x, -4.f * Y4.y);
    } else {
      const int f = tid + (s2 << 10);
      const int p = P0 ^ swzc(pos8c(s2 << 10));
      const int pq = (tid == 0) ? swzc(pos8c((8 - s2) << 10))
                                : (Q0 ^ swzc(pos8c((7 - s2) << 10)));
      float2 k0 = Kc[f];
      float2 k1 = Kc[N2 - f];
      float2 zf = Z[p], zg = Z[pq];
      float2 E = make_float2(zf.x + zg.x, zf.y - zg.y);     // 2E
      float2 O = make_float2(zf.y + zg.y, zg.x - zf.x);     // 2O
      float2 w = tw[f];
      float2 wO = cmul(w, O);
      float2 P = cadd(E, wO);                               // 2 X[f]
      float2 M = csub(E, wO);                               // 2 conj(X[N-f])
      float2 Yf  = cmul(P, k0);
      float2 Ygc = cmul(M, cconj(k1));
      float2 A  = make_float2(Yf.x + Ygc.x, Yf.y + Ygc.y);
      float2 Bc = make_float2(Yf.x - Ygc.x, Yf.y - Ygc.y);
      float2 cb = cmulc(Bc, w);                             // conj(w)*Bc
      Z[p]  = make_float2(A.x - cb.y, A.y + cb.x);
      Z[pq] = make_float2(A.x + cb.y, -A.y + cb.x);         // conj trick
    }
  }
  __syncthreads();

  stg_inv_m1(Z, tid);            // m=1
  __syncthreads();
  stg_inv<2, 256>(Z, T4, tid);   // m=4
  __syncthreads();
  stg_inv<4, 1>(Z, T256, tid);   // m=16
  __syncthreads();
  stg_inv<6, 1>(Z, T64, tid);    // m=64
  __syncthreads();
  stg_inv<8, 1>(Z, T16, tid);    // m=256
  __syncthreads();

  // last inverse stage (m=1024) fused with radix-2 recombine + epilogue
  const float bc = bias[c];
  float2* o2 = (float2*)(out + (size_t)(b * CCH + c) * L_SEQ);
  {
    float2 w1, w2, w3;
    ld3(T4, tid, w1, w2, w3);
    const int sb = swzc(tid);
    float2 A0 = Z[sb],        A1 = Z[sb ^ swzc(1024)];
    float2 A2 = Z[sb ^ swzc(2048)], A3 = Z[sb ^ swzc(3072)];
    dit4(A0, A1, A2, A3, w1, w2, w3);
    const int sc = sb ^ 4096;
    float2 B0 = Z[sc],        B1 = Z[sc ^ swzc(1024)];
    float2 B2 = Z[sc ^ swzc(2048)], B3 = Z[sc ^ swzc(3072)];
    dit4(B0, B1, B2, B3, w1, w2, w3);
    float2 Aa[4] = {A0, A1, A2, A3};
    float2 Bb[4] = {B0, B1, B2, B3};
#pragma unroll
    for (int s = 0; s < 4; ++s) {
      const int i = tid + (s << 10);
      float2 bb = cmulc(Bb[s], tw[i << 1]);
      float2 xv = x2[i];
      o2[i] = make_float2(Aa[s].x + bb.x + xv.x * bc, Aa[s].y + bb.y + xv.y * bc);
    }
  }
}

extern "C" void kernel_launch(void* const* d_in, const int* in_sizes, int n_in,
                              void* d_out, int out_size, void* d_ws, size_t ws_size,
                              hipStream_t stream) {
  const float* x      = (const float*)d_in[0];
  const float* bias   = (const float*)d_in[1];
  const float* z      = (const float*)d_in[2];
  const float* t      = (const float*)d_in[3];
  const float* deltas = (const float*)d_in[4];
  const float* freq   = (const float*)d_in[5];
  const float* w0     = (const float*)d_in[6];
  const float* b0     = (const float*)d_in[7];
  const float* w1     = (const float*)d_in[8];
  const float* b1     = (const float*)d_in[9];
  const float* w2     = (const float*)d_in[10];
  const float* b2     = (const float*)d_in[11];
  const float* wout   = (const float*)d_in[12];
  float* out = (float*)d_out;

  // ws layout: [tw 128K][T4 32K][T16 8K][T64 2K][T256 .5K][h 2M][kfilt 24M][Kf 48M]
  char* p = (char*)d_ws;
  float2* tw   = (float2*)p;             p += (size_t)NFFT * sizeof(float2);
  float4* T4   = (float4*)p;             p += (size_t)1024 * 2 * sizeof(float4);
  float4* T16  = (float4*)p;             p += (size_t)256 * 2 * sizeof(float4);
  float4* T64  = (float4*)p;             p += (size_t)64 * 2 * sizeof(float4);
  float4* T256 = (float4*)p;             p += (size_t)16 * 2 * sizeof(float4);
  float*  h    = (float*)p;              p += (size_t)ODIM * L_SEQ * sizeof(float);
  float*  kfilt= (float*)p;              p += (size_t)CCH * L_SEQ * sizeof(float);
  float2* Kf   = (float2*)p;

  twiddle_kernel<<<70, 256, 0, stream>>>(tw, T4, T16, T64, T256);
  mlp_kernel<<<L_SEQ / ML, 128, 0, stream>>>(z, freq, w0, b0, w1, b1, w2, b2, h);
  kout_kernel<<<(L_SEQ / 64) * (CCH / 64), 256, 0, stream>>>(h, wout, t, deltas, kfilt);

  const size_t lds = (size_t)N2 * sizeof(float2);   // 64 KB
  hipFuncSetAttribute(reinterpret_cast<const void*>(kfft_kernel),
                      hipFuncAttributeMaxDynamicSharedMemorySize, lds);
  hipFuncSetAttribute(reinterpret_cast<const void*>(conv_kernel),
                      hipFuncAttributeMaxDynamicSharedMemorySize, lds);
  kfft_kernel<<<CCH, BLK2, lds, stream>>>(kfilt, tw, T4, T16, T64, T256, Kf);
  conv_kernel<<<BB * CCH, BLK2, lds, stream>>>(x, Kf, bias, tw, T4, T16, T64, T256, out);
}

// Round 15
// 206.777 us; speedup vs baseline: 1.0907x; 1.0907x over previous
//
#include <hip/hip_runtime.h>
#include <math.h>

#define L_SEQ 8192
#define NFFT  16384     // conv length
#define N2    8192      // packed complex FFT length
#define N4    4096      // half (radix-2 block) length
#define CCH   768
#define BB    4
#define EDIM  33
#define ODIM  64
#define BLK   512

#define C_PI8 0.9238795325112867f
#define S_PI8 0.3826834323650898f
#define C_PI4 0.7071067811865476f

// Kf pre-scale: 0.25 (unpack halves) * 1/16384 (fft norm) = 2^-16 (exact)
#define ALPHA 1.52587890625e-05f

// ---------- constexpr index helpers (GF(2)-linear) ----------
constexpr int rev4_12c(int v) {
  int r = 0;
  for (int i = 0; i < 6; ++i) { r = (r << 2) | (v & 3); v >>= 2; }
  return r;
}
constexpr int pos8c(int f) { return ((f & 1) << 12) | rev4_12c(f >> 1); }
constexpr int swzc(int i) { return i ^ ((i >> 4) & 15) ^ ((i >> 8) & 15); }

// ---------- complex helpers ----------
__device__ __forceinline__ float2 cadd(float2 a, float2 b) { return make_float2(a.x + b.x, a.y + b.y); }
__device__ __forceinline__ float2 csub(float2 a, float2 b) { return make_float2(a.x - b.x, a.y - b.y); }
__device__ __forceinline__ float2 cmul(float2 a, float2 b) {
  return make_float2(fmaf(a.x, b.x, -a.y * b.y), fmaf(a.x, b.y, a.y * b.x));
}
// a * conj(w)
__device__ __forceinline__ float2 cmulc(float2 a, float2 w) {
  return make_float2(fmaf(a.x, w.x, a.y * w.y), fmaf(a.y, w.x, -a.x * w.y));
}
__device__ __forceinline__ float2 cconj(float2 a) { return make_float2(a.x, -a.y); }

// ---------- radix-4 butterflies ----------
__device__ __forceinline__ void dif4(float2& x0, float2& x1, float2& x2, float2& x3,
                                     float2 w1, float2 w2, float2 w3) {
  float2 a = cadd(x0, x2), b = csub(x0, x2);
  float2 c = cadd(x1, x3), d = csub(x1, x3);
  x0 = cadd(a, c);
  x1 = cmul(make_float2(b.x + d.y, b.y - d.x), w1);
  x2 = cmul(csub(a, c), w2);
  x3 = cmul(make_float2(b.x - d.y, b.y + d.x), w3);
}
__device__ __forceinline__ void dif4_nw(float2& x0, float2& x1, float2& x2, float2& x3) {
  float2 a = cadd(x0, x2), b = csub(x0, x2);
  float2 c = cadd(x1, x3), d = csub(x1, x3);
  x0 = cadd(a, c);
  x1 = make_float2(b.x + d.y, b.y - d.x);
  x2 = csub(a, c);
  x3 = make_float2(b.x - d.y, b.y + d.x);
}
__device__ __forceinline__ void dit4(float2& x0, float2& x1, float2& x2, float2& x3,
                                     float2 w1, float2 w2, float2 w3) {
  float2 t0 = x0, t1 = cmulc(x1, w1), t2 = cmulc(x2, w2), t3 = cmulc(x3, w3);
  float2 a = cadd(t0, t2), b = csub(t0, t2);
  float2 c = cadd(t1, t3), d = csub(t1, t3);
  x0 = cadd(a, c);
  x1 = make_float2(b.x - d.y, b.y + d.x);
  x2 = csub(a, c);
  x3 = make_float2(b.x + d.y, b.y - d.x);
}
__device__ __forceinline__ void dit4_nw(float2& x0, float2& x1, float2& x2, float2& x3) {
  float2 a = cadd(x0, x2), b = csub(x0, x2);
  float2 c = cadd(x1, x3), d = csub(x1, x3);
  x0 = cadd(a, c);
  x1 = make_float2(b.x - d.y, b.y + d.x);
  x2 = csub(a, c);
  x3 = make_float2(b.x + d.y, b.y - d.x);
}

// triple-table read: entry = {w1, w2, w3, pad} as 2x float4
__device__ __forceinline__ void ld3(const float4* __restrict__ tab, int idx,
                                    float2& w1, float2& w2, float2& w3) {
  float4 a = tab[2 * idx];
  float4 b = tab[2 * idx + 1];
  w1 = make_float2(a.x, a.y);
  w2 = make_float2(a.z, a.w);
  w3 = make_float2(b.x, b.y);
}

// ---------- twiddle + triple tables (standalone, round-10 proven) ----------
__global__ void twiddle_kernel(float2* __restrict__ tw, float4* __restrict__ T4,
                               float4* __restrict__ T16, float4* __restrict__ T64,
                               float4* __restrict__ T256) {
  const int r = blockIdx.x * blockDim.x + threadIdx.x;
  const float C = (float)(6.283185307179586476925286766559 / 16384.0);
  if (r < NFFT) {
    float s, c;
    sincosf(C * (float)r, &s, &c);
    tw[r] = make_float2(c, -s);
  }
  const int j = r - NFFT;
  float4* tab = nullptr;
  int idx = 0, e = 0;
  if (j >= 0 && j < 1024)      { tab = T4;   idx = j;        e = 4 * (j & 255) + 1024 * (j >> 8); }
  else if (j >= 1024 && j < 1280) { tab = T16;  idx = j - 1024; e = 16 * idx; }
  else if (j >= 1280 && j < 1344) { tab = T64;  idx = j - 1280; e = 64 * (idx & 15) + 1024 * (idx >> 4); }
  else if (j >= 1344 && j < 1360) { tab = T256; idx = j - 1344; e = 256 * idx; }
  if (tab) {
    float s1, c1, s2, c2, s3, c3;
    sincosf(C * (float)e, &s1, &c1);
    sincosf(C * (float)(2 * e), &s2, &c2);
    sincosf(C * (float)(3 * e), &s3, &c3);
    tab[2 * idx]     = make_float4(c1, -s1, c2, -s2);
    tab[2 * idx + 1] = make_float4(c3, -s3, 0.f, 0.f);
  }
}

// ---------- MLP: 512 blocks x 128 threads; thread (lrow, oc) computes 8 outputs
// for one l; activations through padded LDS; acc[8] statically indexed ----------
#define ML 16
__global__ __launch_bounds__(128) void mlp_kernel(
    const float* __restrict__ z, const float* __restrict__ freq,
    const float* __restrict__ w0, const float* __restrict__ b0,
    const float* __restrict__ w1, const float* __restrict__ b1,
    const float* __restrict__ w2, const float* __restrict__ b2,
    float* __restrict__ h)            // [64][L]
{
  __shared__ float zs[ML][EDIM];      // stride 33 (odd): conflict-free
  __shared__ float hsA[ML][ODIM + 1]; // stride 65: conflict-free
  __shared__ float hsB[ML][ODIM + 1];
  const int tid = threadIdx.x;
  const int l0 = blockIdx.x * ML;
  const int lrow = tid & 15;
  const int oc = (tid >> 4) * 8;      // 0,8,...,56

  for (int idx = tid; idx < ML * EDIM; idx += 128) {
    int r = idx / EDIM, cc = idx - r * EDIM;
    zs[r][cc] = z[(l0 + r) * EDIM + cc];
  }
  __syncthreads();

  float acc[8], fr[8];
#pragma unroll
  for (int k = 0; k < 8; ++k) { fr[k] = freq[oc + k]; acc[k] = b0[oc + k]; }
#pragma unroll 4
  for (int e = 0; e < EDIM; ++e) {
    const float zv = zs[lrow][e];
#pragma unroll
    for (int j = 0; j < 2; ++j) {
      float4 w4 = *(const float4*)&w0[e * ODIM + oc + 4 * j];
      acc[4*j+0] = fmaf(zv, w4.x, acc[4*j+0]);
      acc[4*j+1] = fmaf(zv, w4.y, acc[4*j+1]);
      acc[4*j+2] = fmaf(zv, w4.z, acc[4*j+2]);
      acc[4*j+3] = fmaf(zv, w4.w, acc[4*j+3]);
    }
  }
#pragma unroll
  for (int k = 0; k < 8; ++k) hsA[lrow][oc + k] = sinf(fr[k] * acc[k]);
  __syncthreads();

#pragma unroll
  for (int k = 0; k < 8; ++k) acc[k] = b1[oc + k];
#pragma unroll 4
  for (int i = 0; i < ODIM; ++i) {
    const float hv = hsA[lrow][i];
#pragma unroll
    for (int j = 0; j < 2; ++j) {
      float4 w4 = *(const float4*)&w1[i * ODIM + oc + 4 * j];
      acc[4*j+0] = fmaf(hv, w4.x, acc[4*j+0]);
      acc[4*j+1] = fmaf(hv, w4.y, acc[4*j+1]);
      acc[4*j+2] = fmaf(hv, w4.z, acc[4*j+2]);
      acc[4*j+3] = fmaf(hv, w4.w, acc[4*j+3]);
    }
  }
#pragma unroll
  for (int k = 0; k < 8; ++k) hsB[lrow][oc + k] = sinf(fr[k] * acc[k]);
  __syncthreads();

#pragma unroll
  for (int k = 0; k < 8; ++k) acc[k] = b2[oc + k];
#pragma unroll 4
  for (int i = 0; i < ODIM; ++i) {
    const float hv = hsB[lrow][i];
#pragma unroll
    for (int j = 0; j < 2; ++j) {
      float4 w4 = *(const float4*)&w2[i * ODIM + oc + 4 * j];
      acc[4*j+0] = fmaf(hv, w4.x, acc[4*j+0]);
      acc[4*j+1] = fmaf(hv, w4.y, acc[4*j+1]);
      acc[4*j+2] = fmaf(hv, w4.z, acc[4*j+2]);
      acc[4*j+3] = fmaf(hv, w4.w, acc[4*j+3]);
    }
  }
#pragma unroll
  for (int k = 0; k < 8; ++k)
    h[(size_t)(oc + k) * L_SEQ + l0 + lrow] = sinf(fr[k] * acc[k]);
}

// ---------- kout: 64x64 tile, 4x4 register micro-tile (round-5 proven version) ----------
__global__ __launch_bounds__(256) void kout_kernel(
    const float* __restrict__ h, const float* __restrict__ wout,
    const float* __restrict__ t, const float* __restrict__ deltas,
    float* __restrict__ k)            // [768][L]
{
  __shared__ float hT[ODIM][64];
  __shared__ float wT[ODIM][64];
  const int lb = blockIdx.x % (L_SEQ / 64);
  const int cb = blockIdx.x / (L_SEQ / 64);
  const int l0 = lb * 64, c0 = cb * 64;
  const int tid = threadIdx.x;
  for (int i = tid; i < ODIM * 16; i += 256) {
    int o = i >> 4, lq = (i & 15) * 4;
    *(float4*)&hT[o][lq] = *(const float4*)&h[(size_t)o * L_SEQ + l0 + lq];
  }
  for (int i = tid; i < ODIM * 16; i += 256) {
    int o = i >> 4, cq = (i & 15) * 4;
    *(float4*)&wT[o][cq] = *(const float4*)&wout[(size_t)o * CCH + c0 + cq];
  }
  __syncthreads();
  const int li = tid & 15, ci = tid >> 4;
  float acc[4][4];
#pragma unroll
  for (int a = 0; a < 4; ++a)
#pragma unroll
    for (int b = 0; b < 4; ++b) acc[a][b] = 0.f;
#pragma unroll 8
  for (int o = 0; o < ODIM; ++o) {
    float4 h4 = *(const float4*)&hT[o][li * 4];
    float4 w4 = *(const float4*)&wT[o][ci * 4];
    const float ha[4] = {h4.x, h4.y, h4.z, h4.w};
    const float wa[4] = {w4.x, w4.y, w4.z, w4.w};
#pragma unroll
    for (int a = 0; a < 4; ++a)
#pragma unroll
      for (int b = 0; b < 4; ++b) acc[a][b] = fmaf(ha[a], wa[b], acc[a][b]);
  }
  float4 t4 = *(const float4*)&t[l0 + li * 4];
  const float ta[4] = {t4.x, t4.y, t4.z, t4.w};
#pragma unroll
  for (int b = 0; b < 4; ++b) {
    const int c = c0 + ci * 4 + b;
    const float dl = fabsf(deltas[c]);
    float4 r;
    r.x = acc[0][b] * expf(-ta[0] * dl);
    r.y = acc[1][b] * expf(-ta[1] * dl);
    r.z = acc[2][b] * expf(-ta[2] * dl);
    r.w = acc[3][b] * expf(-ta[3] * dl);
    *(float4*)&k[(size_t)c * L_SEQ + l0 + li * 4] = r;
  }
}

// ---------- FFT rounds: XOR-linear addressing ----------
// load row + fused radix-2 zero-pad twiddle (upper half)
__device__ __forceinline__ void load_row(float2 xr[4][4], const float2* __restrict__ src,
                                         const float2* __restrict__ tw, int tid) {
  const int h = tid >> 8, u = tid & 255;
#pragma unroll
  for (int s = 0; s < 4; ++s)
#pragma unroll
    for (int t = 0; t < 4; ++t) xr[s][t] = src[u + s * 1024 + t * 256];
  if (h) {
#pragma unroll
    for (int s = 0; s < 4; ++s)
#pragma unroll
      for (int t = 0; t < 4; ++t) xr[s][t] = cmul(xr[s][t], tw[2 * (u + s * 1024 + t * 256)]);
  }
}

__device__ __forceinline__ void fwd_roundA(float2* Z, float2 xr[4][4],
                                           const float4* __restrict__ T4,
                                           const float4* __restrict__ T16, int tid) {
  const int h = tid >> 8, u = tid & 255;
#pragma unroll
  for (int t = 0; t < 4; ++t) {            // stage A: span 1024, e = 4u + 1024t
    float2 w1, w2, w3;
    ld3(T4, t * 256 + u, w1, w2, w3);
    dif4(xr[0][t], xr[1][t], xr[2][t], xr[3][t], w1, w2, w3);
  }
  {                                         // stage B: span 256, e = 16u
    float2 w1, w2, w3;
    ld3(T16, u, w1, w2, w3);
#pragma unroll
    for (int s = 0; s < 4; ++s) dif4(xr[s][0], xr[s][1], xr[s][2], xr[s][3], w1, w2, w3);
  }
  const int sb = swzc((h << 12) + u);
#pragma unroll
  for (int s = 0; s < 4; ++s)
#pragma unroll
    for (int t = 0; t < 4; ++t) Z[sb ^ swzc(s * 1024 + t * 256)] = xr[s][t];
}

__device__ __forceinline__ void fwd_roundB(float2* Z, const float4* __restrict__ T64,
                                           const float4* __restrict__ T256, int tid) {
  const int u = tid & 15, g = (tid >> 4) & 15, h = tid >> 8;
  const int sb = swzc((h << 12) + (g << 8) + u);
  float2 e[4][4];
#pragma unroll
  for (int s = 0; s < 4; ++s)
#pragma unroll
    for (int t = 0; t < 4; ++t) e[s][t] = Z[sb ^ swzc(s * 64 + t * 16)];
#pragma unroll
  for (int t = 0; t < 4; ++t) {            // stage A: span 64, e = 64u + 1024t
    float2 w1, w2, w3;
    ld3(T64, t * 16 + u, w1, w2, w3);
    dif4(e[0][t], e[1][t], e[2][t], e[3][t], w1, w2, w3);
  }
  {                                         // stage B: span 16, e = 256u
    float2 w1, w2, w3;
    ld3(T256, u, w1, w2, w3);
#pragma unroll
    for (int s = 0; s < 4; ++s) dif4(e[s][0], e[s][1], e[s][2], e[s][3], w1, w2, w3);
  }
#pragma unroll
  for (int s = 0; s < 4; ++s)
#pragma unroll
    for (int t = 0; t < 4; ++t) Z[sb ^ swzc(s * 64 + t * 16)] = e[s][t];
}

__device__ __forceinline__ void fwd_roundC(float2* Z, int tid) {
  const int h = tid >> 8, jp = tid & 255;
  const int sb = swzc((h << 12) + (jp << 4));
  float2 e[4][4];
#pragma unroll
  for (int s = 0; s < 4; ++s)
#pragma unroll
    for (int t = 0; t < 4; ++t) e[s][t] = Z[sb ^ (s * 4 + t)];
  dif4_nw(e[0][0], e[1][0], e[2][0], e[3][0]);
  dif4(e[0][1], e[1][1], e[2][1], e[3][1],
       make_float2(C_PI8, -S_PI8), make_float2(C_PI4, -C_PI4), make_float2(S_PI8, -C_PI8));
  dif4(e[0][2], e[1][2], e[2][2], e[3][2],
       make_float2(C_PI4, -C_PI4), make_float2(0.f, -1.f), make_float2(-C_PI4, -C_PI4));
  dif4(e[0][3], e[1][3], e[2][3], e[3][3],
       make_float2(S_PI8, -C_PI8), make_float2(-C_PI4, -C_PI4), make_float2(-C_PI8, S_PI8));
#pragma unroll
  for (int s = 0; s < 4; ++s) dif4_nw(e[s][0], e[s][1], e[s][2], e[s][3]);
#pragma unroll
  for (int s = 0; s < 4; ++s)
#pragma unroll
    for (int t = 0; t < 4; ++t) Z[sb ^ (s * 4 + t)] = e[s][t];
}

__device__ __forceinline__ void inv_roundA(float2* Z, int tid) {
  const int h = tid >> 8, jp = tid & 255;
  const int sb = swzc((h << 12) + (jp << 4));
  float2 e[4][4];
#pragma unroll
  for (int s = 0; s < 4; ++s)
#pragma unroll
    for (int t = 0; t < 4; ++t) e[s][t] = Z[sb ^ (s * 4 + t)];
#pragma unroll
  for (int s = 0; s < 4; ++s) dit4_nw(e[s][0], e[s][1], e[s][2], e[s][3]);
  dit4_nw(e[0][0], e[1][0], e[2][0], e[3][0]);
  dit4(e[0][1], e[1][1], e[2][1], e[3][1],
       make_float2(C_PI8, -S_PI8), make_float2(C_PI4, -C_PI4), make_float2(S_PI8, -C_PI8));
  dit4(e[0][2], e[1][2], e[2][2], e[3][2],
       make_float2(C_PI4, -C_PI4), make_float2(0.f, -1.f), make_float2(-C_PI4, -C_PI4));
  dit4(e[0][3], e[1][3], e[2][3], e[3][3],
       make_float2(S_PI8, -C_PI8), make_float2(-C_PI4, -C_PI4), make_float2(-C_PI8, S_PI8));
#pragma unroll
  for (int s = 0; s < 4; ++s)
#pragma unroll
    for (int t = 0; t < 4; ++t) Z[sb ^ (s * 4 + t)] = e[s][t];
}

__device__ __forceinline__ void inv_roundB(float2* Z, const float4* __restrict__ T64,
                                           const float4* __restrict__ T256, int tid) {
  const int u = tid & 15, g = (tid >> 4) & 15, h = tid >> 8;
  const int sb = swzc((h << 12) + (g << 8) + u);
  float2 e[4][4];
#pragma unroll
  for (int s = 0; s < 4; ++s)
#pragma unroll
    for (int t = 0; t < 4; ++t) e[s][t] = Z[sb ^ swzc(s * 64 + t * 16)];
  {                                         // stage A: span 16 over t, e = 256u
    float2 w1, w2, w3;
    ld3(T256, u, w1, w2, w3);
#pragma unroll
    for (int s = 0; s < 4; ++s) dit4(e[s][0], e[s][1], e[s][2], e[s][3], w1, w2, w3);
  }
#pragma unroll
  for (int t = 0; t < 4; ++t) {            // stage B: span 64 over s, e = 64u + 1024t
    float2 w1, w2, w3;
    ld3(T64, t * 16 + u, w1, w2, w3);
    dit4(e[0][t], e[1][t], e[2][t], e[3][t], w1, w2, w3);
  }
#pragma unroll
  for (int s = 0; s < 4; ++s)
#pragma unroll
    for (int t = 0; t < 4; ++t) Z[sb ^ swzc(s * 64 + t * 16)] = e[s][t];
}

__device__ __forceinline__ void inv_roundC(float2* Z, const float4* __restrict__ T4,
                                           const float4* __restrict__ T16, int tid) {
  const int h = tid >> 8, u = tid & 255;
  const int sb = swzc((h << 12) + u);
  float2 e[4][4];
#pragma unroll
  for (int s = 0; s < 4; ++s)
#pragma unroll
    for (int t = 0; t < 4; ++t) e[s][t] = Z[sb ^ swzc(s * 1024 + t * 256)];
  {                                         // stage A: span 256 over t, e = 16u
    float2 w1, w2, w3;
    ld3(T16, u, w1, w2, w3);
#pragma unroll
    for (int s = 0; s < 4; ++s) dit4(e[s][0], e[s][1], e[s][2], e[s][3], w1, w2, w3);
  }
#pragma unroll
  for (int t = 0; t < 4; ++t) {            // stage B: span 1024 over s, e = 4u + 1024t
    float2 w1, w2, w3;
    ld3(T4, t * 256 + u, w1, w2, w3);
    dit4(e[0][t], e[1][t], e[2][t], e[3][t], w1, w2, w3);
  }
#pragma unroll
  for (int s = 0; s < 4; ++s)
#pragma unroll
    for (int t = 0; t < 4; ++t) Z[sb ^ swzc(s * 1024 + t * 256)] = e[s][t];
}

// ---------- kfft: one channel per WG; store pre-scaled K half-spectrum ----------
__global__ __launch_bounds__(BLK, 4) void kfft_kernel(
    const float* __restrict__ kf, const float2* __restrict__ tw,
    const float4* __restrict__ T4, const float4* __restrict__ T16,
    const float4* __restrict__ T64, const float4* __restrict__ T256,
    float2* __restrict__ Kf)
{
  extern __shared__ float2 Z[];
  const int c = blockIdx.x, tid = threadIdx.x;
  const float2* k2 = (const float2*)(kf + (size_t)c * L_SEQ);
  float2 xr[4][4];
  load_row(xr, k2, tw, tid);
  fwd_roundA(Z, xr, T4, T16, tid);
  __syncthreads();
  fwd_roundB(Z, T64, T256, tid);
  __syncthreads();
  fwd_roundC(Z, tid);
  __syncthreads();

  float2* Kc = Kf + (size_t)c * N2;
  const int P0 = swzc(pos8c(tid));
  const int Q0 = swzc(pos8c(512 - tid));
  const float beta = 0.5f * ALPHA;
#pragma unroll
  for (int s2 = 0; s2 < 8; ++s2) {
    if (s2 == 0 && tid == 0) {
      float2 z0 = Z[0];
      Kc[0] = make_float2(ALPHA * (z0.x + z0.y), ALPHA * (z0.x - z0.y));
      float2 z4 = Z[2];                       // pos8(4096) == 2
      Kc[N4] = make_float2(ALPHA * z4.x, -ALPHA * z4.y);
    } else {
      const int f = tid + s2 * BLK;
      const int p = P0 ^ swzc(pos8c(s2 * 512));
      const int pq = (tid == 0) ? swzc(pos8c(((16 - s2) * 512) & (N2 - 1)))
                                : (Q0 ^ swzc(pos8c((15 - s2) * 512)));
      float2 zf = Z[p], zg = Z[pq];
      float2 E = make_float2(beta * (zf.x + zg.x), beta * (zf.y - zg.y));
      float2 O = make_float2(beta * (zf.y + zg.y), beta * (zg.x - zf.x));
      float2 wO = cmul(tw[f], O);
      Kc[f]      = cadd(E, wO);
      Kc[N2 - f] = cconj(csub(E, wO));
    }
  }
}

// ---------- conv: one (b,c) row per WG; K streamed in mult loop (L2/L3) ----------
__global__ __launch_bounds__(BLK, 4) void conv_kernel(
    const float* __restrict__ x, const float2* __restrict__ Kf,
    const float* __restrict__ bias, const float2* __restrict__ tw,
    const float4* __restrict__ T4, const float4* __restrict__ T16,
    const float4* __restrict__ T64, const float4* __restrict__ T256,
    float* __restrict__ out)
{
  extern __shared__ float2 Z[];
  const int tid = threadIdx.x;
  const int c = blockIdx.x % CCH;
  const int b = blockIdx.x / CCH;
  const float2* x2 = (const float2*)(x + (size_t)(b * CCH + c) * L_SEQ);
  const float2* Kc = Kf + (size_t)c * N2;

  float2 xr[4][4];
  load_row(xr, x2, tw, tid);
  fwd_roundA(Z, xr, T4, T16, tid);
  __syncthreads();
  fwd_roundB(Z, T64, T256, tid);
  __syncthreads();
  fwd_roundC(Z, tid);
  __syncthreads();

  // unpack X, multiply by pre-scaled K (read here, L2/L3-resident),
  // repack spectrum of w = y_even + i*y_odd
  const int P0 = swzc(pos8c(tid));
  const int Q0 = swzc(pos8c(512 - tid));
#pragma unroll
  for (int s2 = 0; s2 < 8; ++s2) {
    if (s2 == 0 && tid == 0) {
      float2 z0 = Z[0];
      float2 k0 = Kc[0];
      float2 k4 = Kc[N4];
      float Y0 = (z0.x + z0.y) * k0.x;
      float Y8 = (z0.x - z0.y) * k0.y;
      Z[0] = make_float2(2.f * (Y0 + Y8), 2.f * (Y0 - Y8));
      float2 z4 = Z[2];
      float2 Y4 = cmul(make_float2(z4.x, -z4.y), k4);
      Z[2] = make_float2(4.f * Y4.x, -4.f * Y4.y);
    } else {
      const int f = tid + s2 * BLK;
      const int fc = (N2 - f) & (N2 - 1);
      const int p = P0 ^ swzc(pos8c(s2 * 512));
      const int pq = (tid == 0) ? swzc(pos8c(((16 - s2) * 512) & (N2 - 1)))
                                : (Q0 ^ swzc(pos8c((15 - s2) * 512)));
      float2 k0 = Kc[f];
      float2 k1 = Kc[fc];
      float2 zf = Z[p], zg = Z[pq];
      float2 E = make_float2(zf.x + zg.x, zf.y - zg.y);     // 2E
      float2 O = make_float2(zf.y + zg.y, zg.x - zf.x);     // 2O
      float2 w = tw[f];
      float2 wO = cmul(w, O);
      float2 P = cadd(E, wO);                               // 2 X[f]
      float2 M = csub(E, wO);                               // 2 conj(X[N-f])
      float2 Yf  = cmul(P, k0);
      float2 Ygc = cmul(M, cconj(k1));
      float2 A  = make_float2(Yf.x + Ygc.x, Yf.y + Ygc.y);
      float2 Bc = make_float2(Yf.x - Ygc.x, Yf.y - Ygc.y);
      float2 cb = cmulc(Bc, w);                             // conj(w)*Bc
      Z[p]  = make_float2(A.x - cb.y, A.y + cb.x);
      // cb2 = cmul(w, conj(Bc)) == conj(cb): saves one cmul
      Z[pq] = make_float2(A.x + cb.y, -A.y + cb.x);
    }
  }
  __syncthreads();
  inv_roundA(Z, tid);
  __syncthreads();
  inv_roundB(Z, T64, T256, tid);
  __syncthreads();
  inv_roundC(Z, T4, T16, tid);
  __syncthreads();

  // fused final radix-2 DIT (low half only) + epilogue, float2 stores
  const float bc = bias[c];
  float2* o2 = (float2*)(out + (size_t)(b * CCH + c) * L_SEQ);
  const int E0 = swzc(tid);
#pragma unroll
  for (int j = 0; j < 8; ++j) {
    const int i = tid + j * 512;
    const int zi = E0 ^ swzc(j * 512);
    float2 a = Z[zi];
    float2 bb = cmulc(Z[zi ^ 4096], tw[2 * i]);   // swzc(4096) == 4096
    float2 xv = x2[i];
    o2[i] = make_float2(a.x + bb.x + xv.x * bc, a.y + bb.y + xv.y * bc);
  }
}

extern "C" void kernel_launch(void* const* d_in, const int* in_sizes, int n_in,
                              void* d_out, int out_size, void* d_ws, size_t ws_size,
                              hipStream_t stream) {
  const float* x      = (const float*)d_in[0];
  const float* bias   = (const float*)d_in[1];
  const float* z      = (const float*)d_in[2];
  const float* t      = (const float*)d_in[3];
  const float* deltas = (const float*)d_in[4];
  const float* freq   = (const float*)d_in[5];
  const float* w0     = (const float*)d_in[6];
  const float* b0     = (const float*)d_in[7];
  const float* w1     = (const float*)d_in[8];
  const float* b1     = (const float*)d_in[9];
  const float* w2     = (const float*)d_in[10];
  const float* b2     = (const float*)d_in[11];
  const float* wout   = (const float*)d_in[12];
  float* out = (float*)d_out;

  // ws layout: [tw 128K][T4 32K][T16 8K][T64 2K][T256 .5K][h 2M][kfilt 24M][Kf 48M]
  char* p = (char*)d_ws;
  float2* tw   = (float2*)p;             p += (size_t)NFFT * sizeof(float2);
  float4* T4   = (float4*)p;             p += (size_t)1024 * 2 * sizeof(float4);
  float4* T16  = (float4*)p;             p += (size_t)256 * 2 * sizeof(float4);
  float4* T64  = (float4*)p;             p += (size_t)64 * 2 * sizeof(float4);
  float4* T256 = (float4*)p;             p += (size_t)16 * 2 * sizeof(float4);
  float*  h    = (float*)p;              p += (size_t)ODIM * L_SEQ * sizeof(float);
  float*  kfilt= (float*)p;              p += (size_t)CCH * L_SEQ * sizeof(float);
  float2* Kf   = (float2*)p;

  twiddle_kernel<<<70, 256, 0, stream>>>(tw, T4, T16, T64, T256);
  mlp_kernel<<<L_SEQ / ML, 128, 0, stream>>>(z, freq, w0, b0, w1, b1, w2, b2, h);
  kout_kernel<<<(L_SEQ / 64) * (CCH / 64), 256, 0, stream>>>(h, wout, t, deltas, kfilt);

  const size_t lds = (size_t)N2 * sizeof(float2);   // 64 KB
  hipFuncSetAttribute(reinterpret_cast<const void*>(kfft_kernel),
                      hipFuncAttributeMaxDynamicSharedMemorySize, lds);
  hipFuncSetAttribute(reinterpret_cast<const void*>(conv_kernel),
                      hipFuncAttributeMaxDynamicSharedMemorySize, lds);
  kfft_kernel<<<CCH, BLK, lds, stream>>>(kfilt, tw, T4, T16, T64, T256, Kf);
  conv_kernel<<<BB * CCH, BLK, lds, stream>>>(x, Kf, bias, tw, T4, T16, T64, T256, out);
}